// Round 5
// baseline (353.368 us; speedup 1.0000x reference)
//
#include <hip/hip_runtime.h>
#include <hip/hip_bf16.h>

// MinGRU: L=2 layers of  h_t = (1-z_t) h_{t-1} + z_t g(pre_t)
// R5: cv back to h-major (coalesced-across-lanes emit reads) but stored via an
// LDS transpose in the GEMM epilogue (16B coalesced stores); NC=64 chunks;
// single fused cast kernel.

#define L_ 2
#define B_ 8
#define S_ 2048
#define D_ 1024
#define H_ 1024
#define M_ (B_*S_)     // 16384
#define NC 64          // chunks per sequence
#define CL (S_/NC)     // 32 steps per chunk (GEMM m-tile 128 = 4 chunks)
#define XN4 (M_*D_/4)
#define WN4 (L_*H_*D_/4)

typedef __bf16    bf16x8 __attribute__((ext_vector_type(8)));
typedef float     f32x4  __attribute__((ext_vector_type(4)));
typedef _Float16  h2     __attribute__((ext_vector_type(2)));

__device__ __forceinline__ ushort f2bf(float f) {
    union { __hip_bfloat16 h; ushort u; } c;
    c.h = __float2bfloat16(f);   // RNE
    return c.u;
}

__device__ __forceinline__ void async16(const void* g, void* l) {
    __builtin_amdgcn_global_load_lds(
        (const __attribute__((address_space(1))) unsigned int*)g,
        (__attribute__((address_space(3))) unsigned int*)l, 16, 0, 0);
}

// One kernel casts x, Wz, Wh to bf16 (fewer launch gaps).
__global__ __launch_bounds__(256) void cast_all(const float* __restrict__ x,
                                                const float* __restrict__ Wz,
                                                const float* __restrict__ Wh,
                                                ushort* __restrict__ xb,
                                                ushort* __restrict__ wzb,
                                                ushort* __restrict__ whb) {
    int i = blockIdx.x * 256 + threadIdx.x;
    const float* src; ushort* dst; int j;
    if (i < XN4)            { src = x;  dst = xb;  j = i; }
    else if (i < XN4 + WN4) { src = Wz; dst = wzb; j = i - XN4; }
    else                    { src = Wh; dst = whb; j = i - XN4 - WN4; }
    float4 v = ((const float4*)src)[j];
    ushort4 o;
    o.x = f2bf(v.x); o.y = f2bf(v.y); o.z = f2bf(v.z); o.w = f2bf(v.w);
    ((ushort4*)dst)[j] = o;
}

// K-loop LDS layout: row R (64 ushorts = 8 chunks of 16B); logical chunk c at
// physical chunk c ^ (R&7).  Offset in ushorts:
#define SWZ(R, c) (((R) << 6) + ((((c) ^ ((R) & 7))) << 3))

// Fused: k = A@Wz^T+bz, pre = A@Wh^T+bh ; cv = (sigmoid(-k), sigmoid(k)*g(pre)) fp16x2,
// cv layout H-MAJOR: cv[(b*S + t)*H + h], written via LDS transpose.
// Tile 128m x 64n = 4 chunks of CL=32; epilogue composes the 4 chunk affines -> Ac, Bc.
__global__ __launch_bounds__(256) void gemm_fused(const ushort* __restrict__ A,
                                                  const ushort* __restrict__ Wz,
                                                  const ushort* __restrict__ Wh,
                                                  const float* __restrict__ bz,
                                                  const float* __restrict__ bh,
                                                  h2* __restrict__ cv,
                                                  float* __restrict__ Ac,
                                                  float* __restrict__ Bc)
{
    __shared__ __align__(16) ushort sm[16384];       // 32 KiB
    ushort* As = sm;            // 128 x 64
    ushort* Zs = sm + 8192;     //  64 x 64
    ushort* Hs = sm + 12288;    //  64 x 64

    const int t    = threadIdx.x;
    const int lane = t & 63;
    const int wave = t >> 6;
    // XCD-aware swizzle: the 16 blocks sharing an A-tile share blockIdx%8 (same XCD).
    const int xcd = (int)blockIdx.x & 7;
    const int k8  = (int)blockIdx.x >> 3;            // 0..255
    const int nblk = k8 & 15;
    const int mblk = ((k8 >> 4) << 3) + xcd;         // 0..127
    const int m0 = mblk * 128;
    const int n0 = nblk * 64;
    const int wm = (wave >> 1) * 64;                 // 0 / 64
    const int wn = (wave & 1) * 32;                  // 0 / 32

    const int srow   = lane >> 3;                    // 0..7
    const int scol_g = (((lane & 7) ^ srow) << 3);   // swizzled source chunk

    f32x4 accz[4][2] = {};
    f32x4 acch[4][2] = {};
    const int lrow = lane & 15;
    const int lcq  = lane >> 4;                      // chunk sub-index 0..3

    for (int kb = 0; kb < D_; kb += 64) {
        __syncthreads();
        #pragma unroll
        for (int i = 0; i < 4; ++i) {                // A: 128 rows
            int r = i*32 + wave*8;
            async16(&A[(size_t)(m0 + r + srow)*D_ + kb + scol_g], &As[r*64]);
        }
        #pragma unroll
        for (int i = 0; i < 2; ++i) {                // Wz, Wh: 64 rows each
            int r = i*32 + wave*8;
            async16(&Wz[(size_t)(n0 + r + srow)*D_ + kb + scol_g], &Zs[r*64]);
            async16(&Wh[(size_t)(n0 + r + srow)*D_ + kb + scol_g], &Hs[r*64]);
        }
        __syncthreads();                             // drains vmcnt -> LDS valid
        #pragma unroll
        for (int kk = 0; kk < 64; kk += 32) {
            const int cq = (kk >> 3) + lcq;          // logical chunk 0..7
            bf16x8 af[4];
            #pragma unroll
            for (int mt = 0; mt < 4; ++mt) {
                int R = wm + mt*16 + lrow;
                uint4 u = *(const uint4*)&As[SWZ(R, cq)];
                af[mt] = __builtin_bit_cast(bf16x8, u);
            }
            #pragma unroll
            for (int nt = 0; nt < 2; ++nt) {
                int R = wn + nt*16 + lrow;
                uint4 uz = *(const uint4*)&Zs[SWZ(R, cq)];
                uint4 uh = *(const uint4*)&Hs[SWZ(R, cq)];
                bf16x8 zb = __builtin_bit_cast(bf16x8, uz);
                bf16x8 hb = __builtin_bit_cast(bf16x8, uh);
                #pragma unroll
                for (int mt = 0; mt < 4; ++mt) {
                    accz[mt][nt] = __builtin_amdgcn_mfma_f32_16x16x32_bf16(af[mt], zb, accz[mt][nt], 0, 0, 0);
                    acch[mt][nt] = __builtin_amdgcn_mfma_f32_16x16x32_bf16(af[mt], hb, acch[mt][nt], 0, 0, 0);
                }
            }
        }
    }

    __syncthreads();                                 // MFMA LDS reads done; reuse LDS
    // Stage cv tile in LDS, layout: h2 index = t_local*64 + phys, where the 16B
    // chunk is XOR-swizzled: phys = (chunk ^ (t_local&15))*4 + within.
    h2* ldscv = (h2*)sm;                             // 128 x 64 h2 = 32 KiB (exact)

    // C/D layout [m89-verified]: col = lane&15, row = (lane>>4)*4 + reg
    const int colq = lane & 15;
    const int rowq = (lane >> 4) * 4;
    const int bq   = m0 >> 11;                       // batch (S=2048)
    const int tb   = m0 & (S_-1);                    // tile's base timestep
    float2 segreg[2][4];
    #pragma unroll
    for (int nt = 0; nt < 2; ++nt) {
        const int n_local = wn + nt*16 + colq;
        const int n = n0 + n_local;
        const float bzv = bz[n];
        const float bhv = bh[n];
        const int chunk4 = n_local >> 2;
        const int within = n_local & 3;
        #pragma unroll
        for (int mt = 0; mt < 4; ++mt) {
            float a = 1.f, bb = 0.f;                 // affine over 4 consecutive t
            #pragma unroll
            for (int r = 0; r < 4; ++r) {
                const int tl = wm + mt*16 + rowq + r;
                float k = accz[mt][nt][r] + bzv;
                float p = acch[mt][nt][r] + bhv;
                float e   = __expf(-fabsf(k));
                float inv = 1.0f / (1.0f + e);
                float z   = (k >= 0.f) ? inv     : e * inv;
                float c   = (k >= 0.f) ? e * inv : inv;
                float g;
                if (p >= 0.f) g = p + 0.5f;
                else { float eg = __expf(p); g = eg / (1.0f + eg); }
                float v = z * g;
                h2 hv; hv[0] = (_Float16)c; hv[1] = (_Float16)v;
                ldscv[tl*64 + ((chunk4 ^ (tl & 15)) << 2) + within] = hv;
                bb = fmaf(c, bb, v);
                a *= c;
            }
            segreg[nt][mt] = make_float2(a, bb);
        }
    }
    __syncthreads();
    // Cooperative coalesced store: 2048 uint4 (8 per thread), h-major global.
    {
        const uint4* l4 = (const uint4*)sm;
        #pragma unroll
        for (int i = 0; i < 8; ++i) {
            int linear = i*256 + t;
            int tl  = linear >> 4;                   // 0..127
            int c16 = linear & 15;                   // 16B chunk within row
            uint4 u = l4[tl*16 + (c16 ^ (tl & 15))];
            *(uint4*)&cv[(size_t)(bq*S_ + tb + tl)*H_ + n0 + (c16 << 2)] = u;
        }
    }
    __syncthreads();
    float2* seg = (float2*)sm;                       // [32 segs][stride 65] float2
    #pragma unroll
    for (int nt = 0; nt < 2; ++nt)
        #pragma unroll
        for (int mt = 0; mt < 4; ++mt) {
            const int sidx = (wm >> 2) + mt*4 + (rowq >> 2);   // 0..31, time-ordered
            seg[sidx*65 + wn + nt*16 + colq] = segreg[nt][mt];
        }
    __syncthreads();
    // four chunks of CL=32 per tile: chunk q <- segs 8q..8q+7
    {
        const int col     = t & 63;
        const int quarter = t >> 6;
        float a = 1.f, bb = 0.f;
        #pragma unroll
        for (int s = 0; s < 8; ++s) {
            float2 e = seg[(quarter*8 + s)*65 + col];
            bb = fmaf(e.x, bb, e.y);
            a *= e.x;
        }
        const int chunk = (tb >> 5) + quarter;
        const int q = (bq*NC + chunk)*H_ + n0 + col;
        Ac[q] = a; Bc[q] = bb;
    }
}

// Scan over the NC chunk-affines per (b,h); emit incoming h per chunk.
__global__ __launch_bounds__(256) void scan_chunk_combine(const float* __restrict__ Ac,
                                                          const float* __restrict__ Bc,
                                                          float* __restrict__ hin)
{
    int q = blockIdx.x * 256 + threadIdx.x;          // 0 .. B*H-1
    int h = q & (H_-1);
    int b = q >> 10;
    float hcur = 0.5f;                               // h0 = g(0) = 0.5
    #pragma unroll
    for (int c = 0; c < NC; ++c) {
        int idx = (b*NC + c)*H_ + h;
        hin[idx] = hcur;
        hcur = fmaf(Ac[idx], hcur, Bc[idx]);
    }
}

// Re-scan each chunk with known incoming h; 2 h per thread, h-major cv so each
// step's wave reads/writes are contiguous across lanes.
__global__ __launch_bounds__(256) void scan_emit(const h2* __restrict__ cv,
                                                 const float* __restrict__ hin,
                                                 float* __restrict__ outf,
                                                 ushort* __restrict__ outb,
                                                 const int write_bf16)
{
    int q = blockIdx.x * 256 + threadIdx.x;          // 0 .. B*NC*H/2-1
    int hp = (q & 511) * 2;                          // h, h+1
    int c  = (q >> 9) & (NC-1);
    int b  = q >> 15;                                // NC*512 = 32768
    size_t base = (size_t)(b*S_ + c*CL) * H_ + hp;
    float2 hv = *(const float2*)&hin[(b*NC + c)*H_ + hp];
    float h0 = hv.x, h1 = hv.y;
    const h2* p = cv + base;
    if (write_bf16) {
        #pragma unroll 4
        for (int tt = 0; tt < CL; ++tt) {
            h2 e0 = p[(size_t)tt * H_];
            h2 e1 = p[(size_t)tt * H_ + 1];
            h0 = fmaf((float)e0[0], h0, (float)e0[1]);
            h1 = fmaf((float)e1[0], h1, (float)e1[1]);
            ushort2 o; o.x = f2bf(h0); o.y = f2bf(h1);
            *(ushort2*)&outb[base + (size_t)tt * H_] = o;
        }
    } else {
        #pragma unroll 4
        for (int tt = 0; tt < CL; ++tt) {
            h2 e0 = p[(size_t)tt * H_];
            h2 e1 = p[(size_t)tt * H_ + 1];
            h0 = fmaf((float)e0[0], h0, (float)e0[1]);
            h1 = fmaf((float)e1[0], h1, (float)e1[1]);
            *(float2*)&outf[base + (size_t)tt * H_] = make_float2(h0, h1);
        }
    }
}

extern "C" void kernel_launch(void* const* d_in, const int* in_sizes, int n_in,
                              void* d_out, int out_size, void* d_ws, size_t ws_size,
                              hipStream_t stream)
{
    const float* x  = (const float*)d_in[0];
    const float* Wz = (const float*)d_in[1];
    const float* bz = (const float*)d_in[2];
    const float* Wh = (const float*)d_in[3];
    const float* bh = (const float*)d_in[4];
    float* out = (float*)d_out;

    // workspace (~108 MiB)
    ushort* xb  = (ushort*)d_ws;                      // M*D bf16        (32 MiB)
    ushort* wzb = xb  + (size_t)M_*D_;                // L*H*D bf16      (4 MiB)
    ushort* whb = wzb + (size_t)L_*H_*D_;             // L*H*D bf16      (4 MiB)
    h2*     cv  = (h2*)(whb + (size_t)L_*H_*D_);      // M*H fp16x2      (64 MiB)
    float*  Ac  = (float*)(cv + (size_t)M_*H_);       // B*NC*H          (2 MiB)
    float*  Bc  = Ac + B_*NC*H_;
    float*  hin = Bc + B_*NC*H_;

    cast_all<<<(XN4 + 2*WN4)/256, 256, 0, stream>>>(x, Wz, Wh, xb, wzb, whb);

    const int gemm_grid = (M_/128) * (H_/64);        // 2048 blocks
    for (int l = 0; l < L_; ++l) {
        gemm_fused<<<gemm_grid, 256, 0, stream>>>(xb,
                                                  wzb + (size_t)l*H_*D_,
                                                  whb + (size_t)l*H_*D_,
                                                  bz + l*H_, bh + l*H_,
                                                  cv, Ac, Bc);
        scan_chunk_combine<<<(B_*H_)/256, 256, 0, stream>>>(Ac, Bc, hin);
        scan_emit<<<(B_*NC*H_/2)/256, 256, 0, stream>>>(cv, hin, out, xb, (l == 0) ? 1 : 0);
    }
}

// Round 6
// 349.052 us; speedup vs baseline: 1.0124x; 1.0124x over previous
//
#include <hip/hip_runtime.h>
#include <hip/hip_bf16.h>

// MinGRU: L=2 layers of  h_t = (1-z_t) h_{t-1} + z_t g(pre_t)
// R6: R3's GEMM (direct h-major cv stores — 64B/quad contiguous, no LDS transpose)
//     + NC=64 (CL=32) with 4-quarter chunk composition in epilogue
//     + emit at 4 h/thread (16B/lane uint4 loads, 4 independent chains)
//     + single fused cast kernel.

#define L_ 2
#define B_ 8
#define S_ 2048
#define D_ 1024
#define H_ 1024
#define M_ (B_*S_)     // 16384
#define NC 64          // chunks per sequence
#define CL (S_/NC)     // 32 steps per chunk (GEMM m-tile 128 = 4 chunks)
#define XN4 (M_*D_/4)
#define WN4 (L_*H_*D_/4)

typedef __bf16    bf16x8 __attribute__((ext_vector_type(8)));
typedef float     f32x4  __attribute__((ext_vector_type(4)));
typedef _Float16  h2     __attribute__((ext_vector_type(2)));

__device__ __forceinline__ ushort f2bf(float f) {
    union { __hip_bfloat16 h; ushort u; } c;
    c.h = __float2bfloat16(f);   // RNE
    return c.u;
}

__device__ __forceinline__ void async16(const void* g, void* l) {
    __builtin_amdgcn_global_load_lds(
        (const __attribute__((address_space(1))) unsigned int*)g,
        (__attribute__((address_space(3))) unsigned int*)l, 16, 0, 0);
}

// One kernel casts x, Wz, Wh to bf16.
__global__ __launch_bounds__(256) void cast_all(const float* __restrict__ x,
                                                const float* __restrict__ Wz,
                                                const float* __restrict__ Wh,
                                                ushort* __restrict__ xb,
                                                ushort* __restrict__ wzb,
                                                ushort* __restrict__ whb) {
    int i = blockIdx.x * 256 + threadIdx.x;
    const float* src; ushort* dst; int j;
    if (i < XN4)            { src = x;  dst = xb;  j = i; }
    else if (i < XN4 + WN4) { src = Wz; dst = wzb; j = i - XN4; }
    else                    { src = Wh; dst = whb; j = i - XN4 - WN4; }
    float4 v = ((const float4*)src)[j];
    ushort4 o;
    o.x = f2bf(v.x); o.y = f2bf(v.y); o.z = f2bf(v.z); o.w = f2bf(v.w);
    ((ushort4*)dst)[j] = o;
}

// K-loop LDS layout: row R (64 ushorts = 8 chunks of 16B); logical chunk c at
// physical chunk c ^ (R&7).  Offset in ushorts:
#define SWZ(R, c) (((R) << 6) + ((((c) ^ ((R) & 7))) << 3))

// Fused: k = A@Wz^T+bz, pre = A@Wh^T+bh ; cv = (sigmoid(-k), sigmoid(k)*g(pre)) fp16x2,
// cv layout H-MAJOR: cv[(b*S + t)*H + h] (direct stores, 64B contiguous per quad).
// Tile 128m x 64n = 4 chunks of CL=32; epilogue composes the 4 chunk affines -> Ac, Bc.
__global__ __launch_bounds__(256) void gemm_fused(const ushort* __restrict__ A,
                                                  const ushort* __restrict__ Wz,
                                                  const ushort* __restrict__ Wh,
                                                  const float* __restrict__ bz,
                                                  const float* __restrict__ bh,
                                                  h2* __restrict__ cv,
                                                  float* __restrict__ Ac,
                                                  float* __restrict__ Bc)
{
    __shared__ __align__(16) ushort sm[16384];       // 32 KiB
    ushort* As = sm;            // 128 x 64
    ushort* Zs = sm + 8192;     //  64 x 64
    ushort* Hs = sm + 12288;    //  64 x 64

    const int t    = threadIdx.x;
    const int lane = t & 63;
    const int wave = t >> 6;
    // XCD-aware swizzle: the 16 blocks sharing an A-tile share blockIdx%8 (same XCD).
    const int xcd = (int)blockIdx.x & 7;
    const int k8  = (int)blockIdx.x >> 3;            // 0..255
    const int nblk = k8 & 15;
    const int mblk = ((k8 >> 4) << 3) + xcd;         // 0..127
    const int m0 = mblk * 128;
    const int n0 = nblk * 64;
    const int wm = (wave >> 1) * 64;                 // 0 / 64
    const int wn = (wave & 1) * 32;                  // 0 / 32

    const int srow   = lane >> 3;                    // 0..7
    const int scol_g = (((lane & 7) ^ srow) << 3);   // swizzled source chunk

    f32x4 accz[4][2] = {};
    f32x4 acch[4][2] = {};
    const int lrow = lane & 15;
    const int lcq  = lane >> 4;                      // chunk sub-index 0..3

    for (int kb = 0; kb < D_; kb += 64) {
        __syncthreads();
        #pragma unroll
        for (int i = 0; i < 4; ++i) {                // A: 128 rows
            int r = i*32 + wave*8;
            async16(&A[(size_t)(m0 + r + srow)*D_ + kb + scol_g], &As[r*64]);
        }
        #pragma unroll
        for (int i = 0; i < 2; ++i) {                // Wz, Wh: 64 rows each
            int r = i*32 + wave*8;
            async16(&Wz[(size_t)(n0 + r + srow)*D_ + kb + scol_g], &Zs[r*64]);
            async16(&Wh[(size_t)(n0 + r + srow)*D_ + kb + scol_g], &Hs[r*64]);
        }
        __syncthreads();                             // drains vmcnt -> LDS valid
        #pragma unroll
        for (int kk = 0; kk < 64; kk += 32) {
            const int cq = (kk >> 3) + lcq;          // logical chunk 0..7
            bf16x8 af[4];
            #pragma unroll
            for (int mt = 0; mt < 4; ++mt) {
                int R = wm + mt*16 + lrow;
                uint4 u = *(const uint4*)&As[SWZ(R, cq)];
                af[mt] = __builtin_bit_cast(bf16x8, u);
            }
            #pragma unroll
            for (int nt = 0; nt < 2; ++nt) {
                int R = wn + nt*16 + lrow;
                uint4 uz = *(const uint4*)&Zs[SWZ(R, cq)];
                uint4 uh = *(const uint4*)&Hs[SWZ(R, cq)];
                bf16x8 zb = __builtin_bit_cast(bf16x8, uz);
                bf16x8 hb = __builtin_bit_cast(bf16x8, uh);
                #pragma unroll
                for (int mt = 0; mt < 4; ++mt) {
                    accz[mt][nt] = __builtin_amdgcn_mfma_f32_16x16x32_bf16(af[mt], zb, accz[mt][nt], 0, 0, 0);
                    acch[mt][nt] = __builtin_amdgcn_mfma_f32_16x16x32_bf16(af[mt], hb, acch[mt][nt], 0, 0, 0);
                }
            }
        }
    }

    __syncthreads();                                 // MFMA LDS reads done; reuse LDS
    float2* seg = (float2*)sm;                       // [32 segs][stride 65] float2

    // C/D layout [m89-verified]: col = lane&15, row = (lane>>4)*4 + reg
    const int colq = lane & 15;
    const int rowq = (lane >> 4) * 4;
    const int bq   = m0 >> 11;                       // batch (S=2048)
    const int tb   = m0 & (S_-1);                    // tile's base timestep
    #pragma unroll
    for (int nt = 0; nt < 2; ++nt) {
        const int n = n0 + wn + nt*16 + colq;        // h index
        const float bzv = bz[n];
        const float bhv = bh[n];
        #pragma unroll
        for (int mt = 0; mt < 4; ++mt) {
            float a = 1.f, bb = 0.f;                 // affine over 4 consecutive t
            #pragma unroll
            for (int r = 0; r < 4; ++r) {
                const int tl = tb + wm + mt*16 + rowq + r;
                float k = accz[mt][nt][r] + bzv;
                float p = acch[mt][nt][r] + bhv;
                float e   = __expf(-fabsf(k));
                float inv = 1.0f / (1.0f + e);
                float z   = (k >= 0.f) ? inv     : e * inv;
                float c   = (k >= 0.f) ? e * inv : inv;
                float g;
                if (p >= 0.f) g = p + 0.5f;
                else { float eg = __expf(p); g = eg / (1.0f + eg); }
                float v = z * g;
                h2 hv; hv[0] = (_Float16)c; hv[1] = (_Float16)v;
                cv[(size_t)(bq*S_ + tl)*H_ + n] = hv;
                bb = fmaf(c, bb, v);
                a *= c;
            }
            const int sidx = (wm >> 2) + mt*4 + (rowq >> 2);   // 0..31, time-ordered
            seg[sidx*65 + wn + nt*16 + colq] = make_float2(a, bb);
        }
    }
    __syncthreads();
    // four chunks of CL=32 per tile: chunk quarter q <- segs 8q..8q+7
    {
        const int col     = t & 63;
        const int quarter = t >> 6;
        float a = 1.f, bb = 0.f;
        #pragma unroll
        for (int s = 0; s < 8; ++s) {
            float2 e = seg[(quarter*8 + s)*65 + col];
            bb = fmaf(e.x, bb, e.y);
            a *= e.x;
        }
        const int chunk = (tb >> 5) + quarter;
        const int q = (bq*NC + chunk)*H_ + n0 + col;
        Ac[q] = a; Bc[q] = bb;
    }
}

// Scan over the NC chunk-affines per (b,h); emit incoming h per chunk.
__global__ __launch_bounds__(256) void scan_chunk_combine(const float* __restrict__ Ac,
                                                          const float* __restrict__ Bc,
                                                          float* __restrict__ hin)
{
    int q = blockIdx.x * 256 + threadIdx.x;          // 0 .. B*H-1
    int h = q & (H_-1);
    int b = q >> 10;
    float hcur = 0.5f;                               // h0 = g(0) = 0.5
    #pragma unroll
    for (int c = 0; c < NC; ++c) {
        int idx = (b*NC + c)*H_ + h;
        hin[idx] = hcur;
        hcur = fmaf(Ac[idx], hcur, Bc[idx]);
    }
}

// Re-scan each chunk with known incoming h; 4 h per thread (one uint4 = 16B/lane
// per step, the coalescing sweet spot; wave reads 1KB contiguous per step).
__global__ __launch_bounds__(256) void scan_emit(const h2* __restrict__ cv,
                                                 const float* __restrict__ hin,
                                                 float* __restrict__ outf,
                                                 ushort* __restrict__ outb,
                                                 const int write_bf16)
{
    int q  = blockIdx.x * 256 + threadIdx.x;         // 0 .. B*NC*H/4-1
    int hp = (q & 255) * 4;                          // h .. h+3
    int c  = (q >> 8) & (NC-1);
    int b  = q >> 14;                                // NC*256 = 16384
    size_t base = (size_t)(b*S_ + c*CL) * H_ + hp;
    float4 hv = *(const float4*)&hin[(b*NC + c)*H_ + hp];
    float h0 = hv.x, h1 = hv.y, h2v = hv.z, h3 = hv.w;
    const h2* p = cv + base;
    if (write_bf16) {
        #pragma unroll 4
        for (int tt = 0; tt < CL; ++tt) {
            union { uint4 u; h2 h[4]; } e;
            e.u = *(const uint4*)&p[(size_t)tt * H_];
            h0  = fmaf((float)e.h[0][0], h0,  (float)e.h[0][1]);
            h1  = fmaf((float)e.h[1][0], h1,  (float)e.h[1][1]);
            h2v = fmaf((float)e.h[2][0], h2v, (float)e.h[2][1]);
            h3  = fmaf((float)e.h[3][0], h3,  (float)e.h[3][1]);
            ushort4 o; o.x = f2bf(h0); o.y = f2bf(h1); o.z = f2bf(h2v); o.w = f2bf(h3);
            *(ushort4*)&outb[base + (size_t)tt * H_] = o;
        }
    } else {
        #pragma unroll 4
        for (int tt = 0; tt < CL; ++tt) {
            union { uint4 u; h2 h[4]; } e;
            e.u = *(const uint4*)&p[(size_t)tt * H_];
            h0  = fmaf((float)e.h[0][0], h0,  (float)e.h[0][1]);
            h1  = fmaf((float)e.h[1][0], h1,  (float)e.h[1][1]);
            h2v = fmaf((float)e.h[2][0], h2v, (float)e.h[2][1]);
            h3  = fmaf((float)e.h[3][0], h3,  (float)e.h[3][1]);
            *(float4*)&outf[base + (size_t)tt * H_] = make_float4(h0, h1, h2v, h3);
        }
    }
}

extern "C" void kernel_launch(void* const* d_in, const int* in_sizes, int n_in,
                              void* d_out, int out_size, void* d_ws, size_t ws_size,
                              hipStream_t stream)
{
    const float* x  = (const float*)d_in[0];
    const float* Wz = (const float*)d_in[1];
    const float* bz = (const float*)d_in[2];
    const float* Wh = (const float*)d_in[3];
    const float* bh = (const float*)d_in[4];
    float* out = (float*)d_out;

    // workspace (~110 MiB)
    ushort* xb  = (ushort*)d_ws;                      // M*D bf16        (32 MiB)
    ushort* wzb = xb  + (size_t)M_*D_;                // L*H*D bf16      (4 MiB)
    ushort* whb = wzb + (size_t)L_*H_*D_;             // L*H*D bf16      (4 MiB)
    h2*     cv  = (h2*)(whb + (size_t)L_*H_*D_);      // M*H fp16x2      (64 MiB)
    float*  Ac  = (float*)(cv + (size_t)M_*H_);       // B*NC*H          (2 MiB)
    float*  Bc  = Ac + B_*NC*H_;
    float*  hin = Bc + B_*NC*H_;

    cast_all<<<(XN4 + 2*WN4)/256, 256, 0, stream>>>(x, Wz, Wh, xb, wzb, whb);

    const int gemm_grid = (M_/128) * (H_/64);        // 2048 blocks
    for (int l = 0; l < L_; ++l) {
        gemm_fused<<<gemm_grid, 256, 0, stream>>>(xb,
                                                  wzb + (size_t)l*H_*D_,
                                                  whb + (size_t)l*H_*D_,
                                                  bz + l*H_, bh + l*H_,
                                                  cv, Ac, Bc);
        scan_chunk_combine<<<(B_*H_)/256, 256, 0, stream>>>(Ac, Bc, hin);
        scan_emit<<<(B_*NC*H_/4)/256, 256, 0, stream>>>(cv, hin, out, xb, (l == 0) ? 1 : 0);
    }
}